// Round 6
// baseline (1801.317 us; speedup 1.0000x reference)
//
#include <hip/hip_runtime.h>
#include <hip/hip_bf16.h>

#define N_NODES 100000
#define N_EDGES 600000
#define SCAN_BLOCKS ((N_NODES + 255) / 256)   // 391

typedef __bf16 bf16;
typedef __bf16 bf16x2 __attribute__((ext_vector_type(2)));
typedef __bf16 bf16x4 __attribute__((ext_vector_type(4)));
typedef __bf16 bf16x8 __attribute__((ext_vector_type(8)));
typedef float f32x4 __attribute__((ext_vector_type(4)));

// ---------------------------------------------------------------------------
// deg[n] = #edges with from==n (== to-degree by reverse-pair symmetry)
__global__ void deg_hist(const int* __restrict__ from, int* __restrict__ deg, int E) {
    int e = blockIdx.x * blockDim.x + threadIdx.x;
    if (e < E) atomicAdd(&deg[from[e]], 1);
}

// ---- CSR build ----
__global__ __launch_bounds__(256) void block_sums(
    const int* __restrict__ deg, int* __restrict__ bsum)
{
    __shared__ int s[256];
    int i = blockIdx.x * 256 + threadIdx.x;
    s[threadIdx.x] = (i < N_NODES) ? deg[i] : 0;
    __syncthreads();
    for (int st = 128; st > 0; st >>= 1) {
        if (threadIdx.x < st) s[threadIdx.x] += s[threadIdx.x + st];
        __syncthreads();
    }
    if (threadIdx.x == 0) bsum[blockIdx.x] = s[0];
}

__global__ __launch_bounds__(256) void scan_partials(
    const int* __restrict__ bsum, int* __restrict__ bpref, int* __restrict__ off)
{
    __shared__ int s[SCAN_BLOCKS];
    for (int i = threadIdx.x; i < SCAN_BLOCKS; i += 256) s[i] = bsum[i];
    __syncthreads();
    if (threadIdx.x == 0) {
        int run = 0;
        for (int i = 0; i < SCAN_BLOCKS; i++) { int t = s[i]; s[i] = run; run += t; }
        off[N_NODES] = run;   // == N_EDGES
    }
    __syncthreads();
    for (int i = threadIdx.x; i < SCAN_BLOCKS; i += 256) bpref[i] = s[i];
}

__global__ __launch_bounds__(256) void block_scan(
    const int* __restrict__ deg, const int* __restrict__ bpref,
    int* __restrict__ off, int* __restrict__ cursor)
{
    __shared__ int s[256];
    int i = blockIdx.x * 256 + threadIdx.x;
    int v = (i < N_NODES) ? deg[i] : 0;
    s[threadIdx.x] = v;
    __syncthreads();
    for (int st = 1; st < 256; st <<= 1) {
        int x = (threadIdx.x >= st) ? s[threadIdx.x - st] : 0;
        __syncthreads();
        s[threadIdx.x] += x;
        __syncthreads();
    }
    if (i < N_NODES) {
        int o = bpref[blockIdx.x] + s[threadIdx.x] - v;   // exclusive
        off[i] = o;
        cursor[i] = o;
    }
}

// se[p] = e (sorted by from), rank[e] = p
__global__ void scatter_csr(const int* __restrict__ from, int* __restrict__ cursor,
                            int* __restrict__ se, int* __restrict__ rank, int E) {
    int e = blockIdx.x * blockDim.x + threadIdx.x;
    if (e < E) {
        int p = atomicAdd(&cursor[from[e]], 1);
        se[p] = e;
        rank[e] = p;
    }
}

// fromP[i] = from[se[i]]; backP[i] = rank[se[i]^1]   (backP is an involution)
__global__ void make_maps(const int* __restrict__ se, const int* __restrict__ from,
                          const int* __restrict__ rank,
                          int* __restrict__ fromP, int* __restrict__ backP, int E) {
    int i = blockIdx.x * blockDim.x + threadIdx.x;
    if (i < E) {
        int e = se[i];
        fromP[i] = from[e];
        backP[i] = rank[e ^ 1];
    }
}

// ---------------------------------------------------------------------------
// C[M,128] = A[M,64] @ B[64,128] + bias   (node-side GEMM, K=64, fp32 vector)
__global__ __launch_bounds__(256) void node_gemm(
    const float* __restrict__ A, const float* __restrict__ B,
    const float* __restrict__ bias, float* __restrict__ C, int M)
{
    __shared__ float As[16][65];
    __shared__ float Bs[16][128];
    int row0 = blockIdx.x * 64;
    int tid = threadIdx.x;
    int tx = tid & 15, ty = tid >> 4;
    float acc[4][8];
    #pragma unroll
    for (int i = 0; i < 4; i++)
        #pragma unroll
        for (int j = 0; j < 8; j++) acc[i][j] = 0.f;

    for (int kk = 0; kk < 64; kk += 16) {
        int m  = tid >> 2;
        int k4 = (tid & 3) * 4;
        float4 v = make_float4(0.f, 0.f, 0.f, 0.f);
        if (row0 + m < M)
            v = *(const float4*)(A + (size_t)(row0 + m) * 64 + kk + k4);
        As[k4 + 0][m] = v.x; As[k4 + 1][m] = v.y;
        As[k4 + 2][m] = v.z; As[k4 + 3][m] = v.w;
        #pragma unroll
        for (int t = 0; t < 2; t++) {
            int id = tid + t * 256;
            int k = id >> 5, n4 = (id & 31) * 4;
            *(float4*)(&Bs[k][n4]) = *(const float4*)(B + (size_t)(kk + k) * 128 + n4);
        }
        __syncthreads();
        #pragma unroll
        for (int k = 0; k < 16; k++) {
            float a[4], b[8];
            #pragma unroll
            for (int i = 0; i < 4; i++) a[i] = As[k][ty * 4 + i];
            #pragma unroll
            for (int j = 0; j < 8; j++) b[j] = Bs[k][tx + j * 16];
            #pragma unroll
            for (int i = 0; i < 4; i++)
                #pragma unroll
                for (int j = 0; j < 8; j++) acc[i][j] += a[i] * b[j];
        }
        __syncthreads();
    }
    #pragma unroll
    for (int i = 0; i < 4; i++) {
        int r = row0 + ty * 4 + i;
        if (r < M) {
            #pragma unroll
            for (int j = 0; j < 8; j++) {
                int c = tx + j * 16;
                C[(size_t)r * 128 + c] = acc[i][j] + bias[c];
            }
        }
    }
}

// ---------------------------------------------------------------------------
// baseP[i,:] = bf16( nodeW1[fromP[i],:] + ef[se[i],:16]@W2 + (W2_b+W3_b) )
__global__ __launch_bounds__(256) void base_sorted(
    const float* __restrict__ nodeW1, const int* __restrict__ fromP,
    const int* __restrict__ se, const float* __restrict__ ef,
    const float* __restrict__ W2, const float* __restrict__ W2b,
    const float* __restrict__ W3b, bf16* __restrict__ baseP)
{
    int tid = threadIdx.x;
    int c0 = (tid & 31) * 4;
    int sub = tid >> 5;                  // 8 edge slots
    float4 w[16];
    #pragma unroll
    for (int k = 0; k < 16; k++) w[k] = *(const float4*)(W2 + k * 128 + c0);
    float4 bias;
    {
        float4 a = *(const float4*)(W2b + c0);
        float4 b = *(const float4*)(W3b + c0);
        bias = make_float4(a.x + b.x, a.y + b.y, a.z + b.z, a.w + b.w);
    }
    #pragma unroll 1
    for (int it = 0; it < 64; ++it) {
        int i = blockIdx.x * 512 + it * 8 + sub;
        if (i >= N_EDGES) break;
        const float* efr = ef + (size_t)se[i] * 16;
        float4 nv = *(const float4*)(nodeW1 + (size_t)fromP[i] * 128 + c0);
        float4 acc = make_float4(bias.x + nv.x, bias.y + nv.y,
                                 bias.z + nv.z, bias.w + nv.w);
        #pragma unroll
        for (int k = 0; k < 16; k++) {
            float s = efr[k];
            acc.x += s * w[k].x; acc.y += s * w[k].y;
            acc.z += s * w[k].z; acc.w += s * w[k].w;
        }
        bf16x4 o;
        o[0] = (bf16)acc.x; o[1] = (bf16)acc.y; o[2] = (bf16)acc.z; o[3] = (bf16)acc.w;
        *(bf16x4*)(baseP + (size_t)i * 128 + c0) = o;
    }
}

// ---------------------------------------------------------------------------
// W3T[n][k] = bf16(W3[k][n]);  U2T[n][k] = bf16(U2[k][n])   (one-time)
__global__ __launch_bounds__(256) void prep_weights(
    const float* __restrict__ W3, const float* __restrict__ U2,
    bf16* __restrict__ W3T, bf16* __restrict__ U2T)
{
    int i = blockIdx.x * 256 + threadIdx.x;
    if (i < 128 * 128) {
        int k = i >> 7, n = i & 127;
        W3T[n * 128 + k] = (bf16)W3[k * 128 + n];
        U2T[n * 128 + k] = (bf16)U2[k * 128 + n];
    }
}

// ---------------------------------------------------------------------------
// Edge-step GEMM v3 (bf16 MFMA), ALL READS SEQUENTIAL (dual-write scheme):
//   A[i,:] = fused ? relu(baseP[i] + S[fromP[i]] - gback[i]) : relu(baseP[i])
//     (gback[i] was scatter-written by the previous step = g_prev[backP[i]])
//   G = A @ B  (B transposed bf16 [n][k], pre-swizzled to LDS)
//   epilogue: gsOut[i,:] = bf16(G[i,:])            (sequential, for segsum)
//             gbOut[backP[i],:] = bf16(G[i,:])     (scattered write, for next step)
// Block = 256 rows; wave w owns rows w*64..+63 in 4 groups of 16.
__global__ __launch_bounds__(256) void edge_mfma_v3(
    const bf16* __restrict__ baseP, const bf16* __restrict__ gback,
    const bf16* __restrict__ S, const int* __restrict__ fromP,
    const int* __restrict__ backP, const bf16* __restrict__ BT,
    bf16* __restrict__ gsOut, bf16* __restrict__ gbOut, int fused)
{
    __shared__ bf16 Bsw[128 * 128];   // 32 KB, fragment-major
    int tid = threadIdx.x;

    #pragma unroll
    for (int t = 0; t < 8; t++) {
        int c = tid + t * 256;            // dst chunk id 0..2047
        int cmr = c & 15;
        int cq  = (c >> 4) & 3;
        int ckt = (c >> 6) & 3;
        int cn  = c >> 8;
        int brow = cn * 16 + cmr;
        int bcol = ckt * 32 + cq * 8;
        *(bf16x8*)&Bsw[(size_t)c * 8] =
            *(const bf16x8*)(BT + (size_t)brow * 128 + bcol);
    }
    __syncthreads();

    int wave = tid >> 6, lane = tid & 63;
    int quad = lane >> 4, mr = lane & 15;

    #pragma unroll 1
    for (int it = 0; it < 4; ++it) {
        int i0 = blockIdx.x * 256 + wave * 64 + it * 16;
        if (i0 >= N_EDGES) break;
        int i = i0 + mr;

        // ---- build this lane's 4 A-fragments in registers (all sequential) ----
        bf16x8 afr[4];
        if (!fused) {
            #pragma unroll
            for (int kt = 0; kt < 4; kt++) {
                bf16x8 bb = *(const bf16x8*)(baseP + (size_t)i * 128 + kt * 32 + quad * 8);
                #pragma unroll
                for (int j = 0; j < 8; j++)
                    afr[kt][j] = (bf16)fmaxf((float)bb[j], 0.f);
            }
        } else {
            const bf16* sr = S     + (size_t)fromP[i] * 128;   // high locality
            const bf16* gr = gback + (size_t)i * 128;          // sequential!
            #pragma unroll
            for (int kt = 0; kt < 4; kt++) {
                int c = kt * 32 + quad * 8;
                bf16x8 bb = *(const bf16x8*)(baseP + (size_t)i * 128 + c);
                bf16x8 gg = *(const bf16x8*)(gr + c);
                bf16x8 ss = *(const bf16x8*)(sr + c);
                #pragma unroll
                for (int j = 0; j < 8; j++) {
                    float v = (float)bb[j] + (float)ss[j] - (float)gg[j];
                    afr[kt][j] = (bf16)fmaxf(v, 0.f);
                }
            }
        }

        // ---- MFMA: 8 col-tiles x 4 k-chunks ----
        f32x4 acc[8];
        #pragma unroll
        for (int n = 0; n < 8; n++) acc[n] = (f32x4){0.f, 0.f, 0.f, 0.f};
        #pragma unroll
        for (int kt = 0; kt < 4; kt++) {
            #pragma unroll
            for (int n = 0; n < 8; n++) {
                bf16x8 b = *(const bf16x8*)&Bsw[(size_t)(((n * 4 + kt) * 64) + lane) * 8];
                acc[n] = __builtin_amdgcn_mfma_f32_16x16x32_bf16(afr[kt], b, acc[n], 0, 0, 0);
            }
        }

        // ---- epilogue: C/D layout col=mr, row=quad*4+reg; pack bf16x2 via
        // lane-pair shfl; store to gsOut[row] (seq) and gbOut[backP[row]] ----
        int brow[4];
        #pragma unroll
        for (int reg = 0; reg < 4; reg++) brow[reg] = backP[i0 + quad * 4 + reg];
        #pragma unroll
        for (int np = 0; np < 4; np++) {
            int n0 = np * 2;
            #pragma unroll
            for (int reg = 0; reg < 4; reg++) {
                float v0 = acc[n0][reg], v1 = acc[n0 + 1][reg];
                float o0 = __shfl_xor(v0, 1);
                float o1 = __shfl_xor(v1, 1);
                bf16x2 pk;
                int colb;
                if ((mr & 1) == 0) {
                    pk[0] = (bf16)v0; pk[1] = (bf16)o0;
                    colb = n0 * 16 + mr;
                } else {
                    pk[0] = (bf16)o1; pk[1] = (bf16)v1;
                    colb = (n0 + 1) * 16 + (mr ^ 1);
                }
                int row = i0 + quad * 4 + reg;
                if (gsOut) *(bf16x2*)(gsOut + (size_t)row * 128 + colb) = pk;
                *(bf16x2*)(gbOut + (size_t)brow[reg] * 128 + colb) = pk;
            }
        }
    }
}

// ---------------------------------------------------------------------------
// Streaming segment sum over contiguous buckets, 2 rows per iteration:
// half-wave h processes rows o0+h, o0+h+2, ...; lanes cover 4 cols each.
// FP32OUT=0: S[n,:]  = bf16(sum);  FP32OUT=1: agg[n,:] = fp32 sum.
template<int FP32OUT>
__global__ __launch_bounds__(256) void segsum2(
    const bf16* __restrict__ g, const int* __restrict__ off,
    bf16* __restrict__ Sout, float* __restrict__ aggout)
{
    int n = blockIdx.x * 4 + (threadIdx.x >> 6);
    if (n >= N_NODES) return;
    int lane = threadIdx.x & 63;
    int half = lane >> 5;
    int c0 = (lane & 31) * 4;
    int o0 = off[n], o1 = off[n + 1];
    float a0 = 0.f, a1 = 0.f, a2 = 0.f, a3 = 0.f;
    for (int i = o0 + half; i < o1; i += 2) {
        bf16x4 v = *(const bf16x4*)(g + (size_t)i * 128 + c0);
        a0 += (float)v[0]; a1 += (float)v[1];
        a2 += (float)v[2]; a3 += (float)v[3];
    }
    a0 += __shfl_xor(a0, 32); a1 += __shfl_xor(a1, 32);
    a2 += __shfl_xor(a2, 32); a3 += __shfl_xor(a3, 32);
    if (half == 0) {
        if (FP32OUT) {
            *(float4*)(aggout + (size_t)n * 128 + c0) = make_float4(a0, a1, a2, a3);
        } else {
            bf16x4 o;
            o[0] = (bf16)a0; o[1] = (bf16)a1; o[2] = (bf16)a2; o[3] = (bf16)a3;
            *(bf16x4*)(Sout + (size_t)n * 128 + c0) = o;
        }
    }
}

// ---------------------------------------------------------------------------
// out[n,:] = relu(U1x[n,:] + agg[n,:] + deg[n] * U2_b[:])
__global__ __launch_bounds__(256) void final_out(
    const float* __restrict__ U1x, const float* __restrict__ agg,
    const int* __restrict__ deg, const float* __restrict__ U2b,
    float* __restrict__ out)
{
    int gid = blockIdx.x * 256 + threadIdx.x;
    int n  = gid >> 5;
    if (n >= N_NODES) return;
    int c4 = gid & 31;
    float d = (float)deg[n];
    float4 a  = *(const float4*)(U1x + (size_t)n * 128 + c4 * 4);
    float4 ag = *(const float4*)(agg + (size_t)n * 128 + c4 * 4);
    float4 ub = *(const float4*)(U2b + c4 * 4);
    float4 r;
    r.x = fmaxf(a.x + ag.x + d * ub.x, 0.f);
    r.y = fmaxf(a.y + ag.y + d * ub.y, 0.f);
    r.z = fmaxf(a.z + ag.z + d * ub.z, 0.f);
    r.w = fmaxf(a.w + ag.w + d * ub.w, 0.f);
    *(float4*)(out + (size_t)n * 128 + c4 * 4) = r;
}

// ---------------------------------------------------------------------------
extern "C" void kernel_launch(void* const* d_in, const int* in_sizes, int n_in,
                              void* d_out, int out_size, void* d_ws, size_t ws_size,
                              hipStream_t stream) {
    const float* nf  = (const float*)d_in[0];
    const float* ef  = (const float*)d_in[1];
    // d_in[2] edge_hiddens: zeros -> h1 = relu(base); first GEMM uses fused=0
    const int* edges = (const int*)d_in[3];
    const int* from  = edges;
    const float* W1w = (const float*)d_in[4];
    const float* W1b = (const float*)d_in[5];
    const float* W2w = (const float*)d_in[6];
    const float* W2b = (const float*)d_in[7];
    const float* W3w = (const float*)d_in[8];
    const float* W3b = (const float*)d_in[9];
    const float* U1w = (const float*)d_in[10];
    const float* U1b = (const float*)d_in[11];
    const float* U2w = (const float*)d_in[12];
    const float* U2b = (const float*)d_in[13];
    float* out = (float*)d_out;

    const size_t NODE_MAT = (size_t)N_NODES * 128;
    const size_t EDGE_MAT = (size_t)N_EDGES * 128;
    char* w = (char*)d_ws;
    float* nodeW1 = (float*)w; w += NODE_MAT * 4;        // reused as U1x
    float* agg    = (float*)w; w += NODE_MAT * 4;
    bf16*  S      = (bf16*)w;  w += NODE_MAT * 2;
    bf16*  baseP  = (bf16*)w;  w += EDGE_MAT * 2;
    bf16*  gs     = (bf16*)w;  w += EDGE_MAT * 2;        // sorted-order G
    bf16*  gbA    = (bf16*)w;  w += EDGE_MAT * 2;        // back-permuted G (ping)
    bf16*  gbB    = (bf16*)w;  w += EDGE_MAT * 2;        // back-permuted G (pong)
    bf16*  W3T    = (bf16*)w;  w += 128 * 128 * 2;
    bf16*  U2T    = (bf16*)w;  w += 128 * 128 * 2;
    int*   deg    = (int*)w;   w += (size_t)N_NODES * 4;
    int*   off    = (int*)w;   w += (size_t)(N_NODES + 1) * 4;
    int*   cursor = (int*)w;   w += (size_t)N_NODES * 4;
    int*   bsum   = (int*)w;   w += (size_t)SCAN_BLOCKS * 4;
    int*   bpref  = (int*)w;   w += (size_t)SCAN_BLOCKS * 4;
    int*   se     = (int*)w;   w += (size_t)N_EDGES * 4;
    int*   rank   = (int*)w;   w += (size_t)N_EDGES * 4;
    int*   fromP  = (int*)w;   w += (size_t)N_EDGES * 4;
    int*   backP  = (int*)w;   w += (size_t)N_EDGES * 4;

    // ---- CSR build + sorted-space maps ----
    hipMemsetAsync(deg, 0, (size_t)N_NODES * 4, stream);
    deg_hist<<<(N_EDGES + 255) / 256, 256, 0, stream>>>(from, deg, N_EDGES);
    block_sums<<<SCAN_BLOCKS, 256, 0, stream>>>(deg, bsum);
    scan_partials<<<1, 256, 0, stream>>>(bsum, bpref, off);
    block_scan<<<SCAN_BLOCKS, 256, 0, stream>>>(deg, bpref, off, cursor);
    scatter_csr<<<(N_EDGES + 255) / 256, 256, 0, stream>>>(from, cursor, se, rank, N_EDGES);
    make_maps<<<(N_EDGES + 255) / 256, 256, 0, stream>>>(se, from, rank, fromP, backP, N_EDGES);

    // ---- loop-invariant precompute ----
    prep_weights<<<(128 * 128 + 255) / 256, 256, 0, stream>>>(W3w, U2w, W3T, U2T);
    node_gemm<<<(N_NODES + 63) / 64, 256, 0, stream>>>(nf, W1w, W1b, nodeW1, N_NODES);
    base_sorted<<<(N_EDGES + 511) / 512, 256, 0, stream>>>(
        nodeW1, fromP, se, ef, W2w, W2b, W3b, baseP);

    // ---- message passing (dual-write ping-pong on gback) ----
    const int EGRID = (N_EDGES + 255) / 256;   // 2344
    const int SGRID = (N_NODES + 3) / 4;
    bf16* GB[2] = {gbA, gbB};
    int cur = 0;
    // step 1: h1 = relu(base)
    edge_mfma_v3<<<EGRID, 256, 0, stream>>>(
        baseP, GB[cur], S, fromP, backP, W3T, gs, GB[cur], 0);
    segsum2<0><<<SGRID, 256, 0, stream>>>(gs, off, S, agg);
    // steps 2..5
    for (int it = 1; it < 5; ++it) {
        edge_mfma_v3<<<EGRID, 256, 0, stream>>>(
            baseP, GB[cur], S, fromP, backP, W3T, gs, GB[cur ^ 1], 1);
        cur ^= 1;
        segsum2<0><<<SGRID, 256, 0, stream>>>(gs, off, S, agg);
    }
    // ---- readout: B = U2T; only gback written; to-side sum is a pure stream ----
    edge_mfma_v3<<<EGRID, 256, 0, stream>>>(
        baseP, GB[cur], S, fromP, backP, U2T, nullptr, GB[cur ^ 1], 1);
    cur ^= 1;
    segsum2<1><<<SGRID, 256, 0, stream>>>(GB[cur], off, S, agg);

    node_gemm<<<(N_NODES + 63) / 64, 256, 0, stream>>>(nf, U1w, U1b, nodeW1, N_NODES);
    final_out<<<(N_NODES * 32 + 255) / 256, 256, 0, stream>>>(nodeW1, agg, deg, U2b, out);
}